// Round 5
// baseline (172.536 us; speedup 1.0000x reference)
//
#include <hip/hip_runtime.h>
#include <math.h>

#define BB 32
#define NN 2048
#define TB 256            // threads per block
#define QT 8              // queries per thread -> 2048 = NN per block
#define RCH 16            // ref chunks (split of the min over refs)
#define MCH (NN / RCH)    // 128 refs per chunk

// ws layout:
//   part [RCH][2*BB][NN] floats                 8 MB   (no init needed)
//   bsum [2*BB][8] floats                       2 KB   (no init needed)
//   cnts [65] uint32 at CNT_F floats offset     zeroed by tiny memset
#define PART_F ((size_t)RCH * 2 * BB * NN)
#define BSUM_F ((size_t)2 * BB * 8)
#define CNT_F  (PART_F + BSUM_F)

__device__ __forceinline__ float wred(float v) {
#pragma unroll
    for (int o = 32; o > 0; o >>= 1) v += __shfl_down(v, o, 64);
    return v;
}

// Single fused kernel. grid (1, BB, 2*RCH); blockIdx.z = rc*2 + role.
// Phase A: per-chunk partial min (all 1024 blocks).
// Phase B: per-(b,role) finisher (last of the 16 rc-blocks) combines planes.
// Phase C: global finisher (last of the 64) assembles the 4 outputs.
// Last-arrival delegation only — no spinning, no dispatch-order assumption.
__global__ __launch_bounds__(256) void k_all(
    const float* __restrict__ pred, const float* __restrict__ tgt,
    const float* __restrict__ smask, float* __restrict__ part,
    float* __restrict__ bsum, unsigned int* __restrict__ cnts)
{
    __shared__ float sa[MCH], sb[MCH], sc[MCH];
    __shared__ float sred[5 * 4];
    __shared__ int sflag;

    const int tid  = threadIdx.x;
    const int b    = blockIdx.y;
    const int role = blockIdx.z & 1;
    const int rc   = blockIdx.z >> 1;

    // ---------------- Phase A: partial min over one ref chunk ----------------
    const float* q = role ? tgt : pred;
    const float* r = role ? pred : tgt;
    const float* rb = r + ((size_t)b * NN + (size_t)rc * MCH) * 3;

    if (tid < MCH) {
        float rx = rb[3 * tid + 0];
        float ry = rb[3 * tid + 1];
        float rv = rb[3 * tid + 2];
        if (rv != 1.0f) { rx = 1.0e9f; ry = 1.0e9f; }   // d2 ~ 2e18, never wins
        sa[tid] = -2.0f * rx;
        sb[tid] = -2.0f * ry;
        sc[tid] = fmaf(rx, rx, ry * ry);
    }
    __syncthreads();

    const float* qb_ = q + (size_t)b * NN * 3;
    float px[QT], py[QT], mn[QT];
#pragma unroll
    for (int j = 0; j < QT; j++) {
        int qi = tid + j * TB;
        px[j] = qb_[3 * qi + 0];
        py[j] = qb_[3 * qi + 1];
        mn[j] = 3.4e38f;
    }

    // 8 refs/iter: 6 uniform ds_read_b128 (broadcast), per query 16 fma +
    // a 4x v_min3 tree -> 2.5 VALU/pair.
#pragma unroll 2
    for (int m = 0; m < MCH; m += 8) {
        float4 a0 = *(const float4*)&sa[m], a1 = *(const float4*)&sa[m + 4];
        float4 b0 = *(const float4*)&sb[m], b1 = *(const float4*)&sb[m + 4];
        float4 c0 = *(const float4*)&sc[m], c1 = *(const float4*)&sc[m + 4];
#pragma unroll
        for (int j = 0; j < QT; j++) {
            float s0 = fmaf(px[j], a0.x, fmaf(py[j], b0.x, c0.x));
            float s1 = fmaf(px[j], a0.y, fmaf(py[j], b0.y, c0.y));
            float s2 = fmaf(px[j], a0.z, fmaf(py[j], b0.z, c0.z));
            float s3 = fmaf(px[j], a0.w, fmaf(py[j], b0.w, c0.w));
            float s4 = fmaf(px[j], a1.x, fmaf(py[j], b1.x, c1.x));
            float s5 = fmaf(px[j], a1.y, fmaf(py[j], b1.y, c1.y));
            float s6 = fmaf(px[j], a1.z, fmaf(py[j], b1.z, c1.z));
            float s7 = fmaf(px[j], a1.w, fmaf(py[j], b1.w, c1.w));
            float u = fminf(fminf(s0, s1), s2);           // -> v_min3
            float v = fminf(fminf(s3, s4), s5);           // -> v_min3
            float w = fminf(fminf(s6, s7), mn[j]);        // -> v_min3
            mn[j] = fminf(fminf(u, v), w);                // -> v_min3
        }
    }

#pragma unroll
    for (int j = 0; j < QT; j++) {
        int qi = tid + j * TB;
        float qn = fmaf(px[j], px[j], py[j] * py[j]);
        part[((size_t)rc * (2 * BB) + role * BB + b) * NN + qi] = qn + mn[j];
    }

    __threadfence();   // release part-plane writes (device scope, cross-XCD)
    if (tid == 0)
        sflag = (atomicAdd(&cnts[role * BB + b], 1u) == RCH - 1);
    __syncthreads();
    if (!sflag) return;

    // ---------- Phase B: one block per (b,role) combines the 16 planes ------
    __threadfence();   // acquire: other blocks' planes now visible

    float acc[5] = {0.f, 0.f, 0.f, 0.f, 0.f};
#pragma unroll
    for (int j = 0; j < QT; j++) {
        int qi = tid + j * TB;
        float m = 3.4e38f;
#pragma unroll
        for (int k = 0; k < RCH; k++)
            m = fminf(m, part[((size_t)k * (2 * BB) + role * BB + b) * NN + qi]);

        const float* qp = qb_ + 3 * qi;
        float qvf = (qp[2] == 1.0f) ? 1.0f : 0.0f;
        acc[0] += sqrtf(fmaxf(m, 1e-12f)) * qvf;
        acc[1] += qvf;

        if (role == 0) {
            const float* tp = tgt + ((size_t)b * NN + qi) * 3;
            float vm = (tp[2] == 1.0f) ? 1.0f : 0.0f;
            float dx = qp[0] - tp[0], dy = qp[1] - tp[1];
            float e2 = fmaf(dx, dx, dy * dy);
            float s0 = smask[((size_t)b * NN + qi) * 2 + 0];
            float s1 = smask[((size_t)b * NN + qi) * 2 + 1];
            float tm = fminf(fmaxf(s0 + s1, 0.0f), 1.0f) * vm;
            acc[2] += e2 * vm;
            acc[3] += e2 * tm;
            acc[4] += tm;
        }
    }

    const int wave = tid >> 6, lane = tid & 63;
#pragma unroll
    for (int i = 0; i < 5; i++) {
        float rv = wred(acc[i]);
        if (lane == 0) sred[i * 4 + wave] = rv;
    }
    __syncthreads();
    if (tid < 5)
        bsum[(role * BB + b) * 8 + tid] =
            sred[tid * 4 + 0] + sred[tid * 4 + 1] + sred[tid * 4 + 2] + sred[tid * 4 + 3];

    __threadfence();   // release bsum record
    if (tid == 0)
        sflag = (atomicAdd(&cnts[64], 1u) == 2 * BB - 1);
    __syncthreads();
    if (!sflag) return;

    // ---------------- Phase C: last finisher assembles outputs --------------
    __threadfence();   // acquire all bsum records
    if (tid >= 64) return;
    const int l = tid;

    float ch = 0.f, pt = 0.f, st = 0.f, mk = 0.f;
    if (l < BB) {
        const float* r0 = &bsum[(0 * BB + l) * 8];
        const float* r1 = &bsum[(1 * BB + l) * 8];
        float sp = r0[0], cp = r0[1];
        float s1_ = r1[0], ct = r1[1];
        float mp = sp / fmaxf(cp, 1.0f);
        float mt = s1_ / fmaxf(ct, 1.0f);
        ch = (cp > 0.0f && ct > 0.0f) ? 0.5f * (mp + mt) : 0.0f;
        pt = r0[2]; st = r0[3]; mk = r0[4];
    }
    ch = wred(ch); pt = wred(pt); st = wred(st); mk = wred(mk);

    if (l == 0) {
        float loss_chamfer = ch / (float)BB;
        const float denom = (float)BB * (float)NN * 2.0f;
        float loss_point = pt / denom;
        float loss_struct = (mk > 0.0f) ? st / denom : 0.0f;
        float* out = (float*)cnts;   // unused; real out passed below
        (void)out;
        // outputs written via the global pointer captured in params:
    }
    // write outputs (lane 0 only)
    if (l == 0) {
        // recompute locals kept above
    }
}

// Output writing needs d_out; simplest is a dedicated param. Redefine kernel
// properly below (the above placeholder writes are factored here).
__global__ __launch_bounds__(64) void k_unused() {}

extern "C" void kernel_launch(void* const* d_in, const int* in_sizes, int n_in,
                              void* d_out, int out_size, void* d_ws, size_t ws_size,
                              hipStream_t stream);

// --- real kernel (with out pointer) ---
__global__ __launch_bounds__(256) void k_fused(
    const float* __restrict__ pred, const float* __restrict__ tgt,
    const float* __restrict__ smask, float* __restrict__ part,
    float* __restrict__ bsum, unsigned int* __restrict__ cnts,
    float* __restrict__ out)
{
    __shared__ float sa[MCH], sb[MCH], sc[MCH];
    __shared__ float sred[5 * 4];
    __shared__ int sflag;

    const int tid  = threadIdx.x;
    const int b    = blockIdx.y;
    const int role = blockIdx.z & 1;
    const int rc   = blockIdx.z >> 1;

    const float* q = role ? tgt : pred;
    const float* r = role ? pred : tgt;
    const float* rb = r + ((size_t)b * NN + (size_t)rc * MCH) * 3;

    if (tid < MCH) {
        float rx = rb[3 * tid + 0];
        float ry = rb[3 * tid + 1];
        float rv = rb[3 * tid + 2];
        if (rv != 1.0f) { rx = 1.0e9f; ry = 1.0e9f; }
        sa[tid] = -2.0f * rx;
        sb[tid] = -2.0f * ry;
        sc[tid] = fmaf(rx, rx, ry * ry);
    }
    __syncthreads();

    const float* qb_ = q + (size_t)b * NN * 3;
    float px[QT], py[QT], mn[QT];
#pragma unroll
    for (int j = 0; j < QT; j++) {
        int qi = tid + j * TB;
        px[j] = qb_[3 * qi + 0];
        py[j] = qb_[3 * qi + 1];
        mn[j] = 3.4e38f;
    }

#pragma unroll 2
    for (int m = 0; m < MCH; m += 8) {
        float4 a0 = *(const float4*)&sa[m], a1 = *(const float4*)&sa[m + 4];
        float4 b0 = *(const float4*)&sb[m], b1 = *(const float4*)&sb[m + 4];
        float4 c0 = *(const float4*)&sc[m], c1 = *(const float4*)&sc[m + 4];
#pragma unroll
        for (int j = 0; j < QT; j++) {
            float s0 = fmaf(px[j], a0.x, fmaf(py[j], b0.x, c0.x));
            float s1 = fmaf(px[j], a0.y, fmaf(py[j], b0.y, c0.y));
            float s2 = fmaf(px[j], a0.z, fmaf(py[j], b0.z, c0.z));
            float s3 = fmaf(px[j], a0.w, fmaf(py[j], b0.w, c0.w));
            float s4 = fmaf(px[j], a1.x, fmaf(py[j], b1.x, c1.x));
            float s5 = fmaf(px[j], a1.y, fmaf(py[j], b1.y, c1.y));
            float s6 = fmaf(px[j], a1.z, fmaf(py[j], b1.z, c1.z));
            float s7 = fmaf(px[j], a1.w, fmaf(py[j], b1.w, c1.w));
            float u = fminf(fminf(s0, s1), s2);
            float v = fminf(fminf(s3, s4), s5);
            float w = fminf(fminf(s6, s7), mn[j]);
            mn[j] = fminf(fminf(u, v), w);
        }
    }

#pragma unroll
    for (int j = 0; j < QT; j++) {
        int qi = tid + j * TB;
        float qn = fmaf(px[j], px[j], py[j] * py[j]);
        part[((size_t)rc * (2 * BB) + role * BB + b) * NN + qi] = qn + mn[j];
    }

    __threadfence();
    if (tid == 0)
        sflag = (atomicAdd(&cnts[role * BB + b], 1u) == RCH - 1);
    __syncthreads();
    if (!sflag) return;

    // Phase B
    __threadfence();
    float acc0 = 0.f, acc1 = 0.f, acc2 = 0.f, acc3 = 0.f, acc4 = 0.f;
#pragma unroll
    for (int j = 0; j < QT; j++) {
        int qi = tid + j * TB;
        float m = 3.4e38f;
#pragma unroll
        for (int k = 0; k < RCH; k++)
            m = fminf(m, part[((size_t)k * (2 * BB) + role * BB + b) * NN + qi]);

        const float* qp = qb_ + 3 * qi;
        float qvf = (qp[2] == 1.0f) ? 1.0f : 0.0f;
        acc0 += sqrtf(fmaxf(m, 1e-12f)) * qvf;
        acc1 += qvf;

        if (role == 0) {
            const float* tp = tgt + ((size_t)b * NN + qi) * 3;
            float vm = (tp[2] == 1.0f) ? 1.0f : 0.0f;
            float dx = qp[0] - tp[0], dy = qp[1] - tp[1];
            float e2 = fmaf(dx, dx, dy * dy);
            float s0 = smask[((size_t)b * NN + qi) * 2 + 0];
            float s1 = smask[((size_t)b * NN + qi) * 2 + 1];
            float tm = fminf(fmaxf(s0 + s1, 0.0f), 1.0f) * vm;
            acc2 += e2 * vm;
            acc3 += e2 * tm;
            acc4 += tm;
        }
    }

    float accs[5] = {acc0, acc1, acc2, acc3, acc4};
    const int wave = tid >> 6, lane = tid & 63;
#pragma unroll
    for (int i = 0; i < 5; i++) {
        float rv = wred(accs[i]);
        if (lane == 0) sred[i * 4 + wave] = rv;
    }
    __syncthreads();
    if (tid < 5)
        bsum[(role * BB + b) * 8 + tid] =
            sred[tid * 4 + 0] + sred[tid * 4 + 1] + sred[tid * 4 + 2] + sred[tid * 4 + 3];

    __threadfence();
    if (tid == 0)
        sflag = (atomicAdd(&cnts[64], 1u) == 2 * BB - 1);
    __syncthreads();
    if (!sflag) return;

    // Phase C
    __threadfence();
    if (tid >= 64) return;
    const int l = tid;

    float ch = 0.f, pt = 0.f, st = 0.f, mk = 0.f;
    if (l < BB) {
        const float* r0 = &bsum[(0 * BB + l) * 8];
        const float* r1 = &bsum[(1 * BB + l) * 8];
        float sp = r0[0], cp = r0[1];
        float s1_ = r1[0], ct = r1[1];
        float mp = sp / fmaxf(cp, 1.0f);
        float mt = s1_ / fmaxf(ct, 1.0f);
        ch = (cp > 0.0f && ct > 0.0f) ? 0.5f * (mp + mt) : 0.0f;
        pt = r0[2]; st = r0[3]; mk = r0[4];
    }
    ch = wred(ch); pt = wred(pt); st = wred(st); mk = wred(mk);

    if (l == 0) {
        float loss_chamfer = ch / (float)BB;
        const float denom = (float)BB * (float)NN * 2.0f;
        float loss_point = pt / denom;
        float loss_struct = (mk > 0.0f) ? st / denom : 0.0f;
        out[0] = loss_point + 5.0f * loss_chamfer + 2.0f * loss_struct;
        out[1] = loss_point;
        out[2] = 0.0f;
        out[3] = loss_chamfer;
    }
}

extern "C" void kernel_launch(void* const* d_in, const int* in_sizes, int n_in,
                              void* d_out, int out_size, void* d_ws, size_t ws_size,
                              hipStream_t stream)
{
    const float* pred  = (const float*)d_in[0];
    const float* tgt   = (const float*)d_in[1];
    const float* smask = (const float*)d_in[2];
    float* out = (float*)d_out;
    float* ws  = (float*)d_ws;

    float* part = ws;
    float* bsum = ws + PART_F;
    unsigned int* cnts = (unsigned int*)(ws + CNT_F);

    // zero the 65 arrival counters (512 B) — only init the kernel needs
    hipMemsetAsync((void*)cnts, 0, 512, stream);

    k_fused<<<dim3(1, BB, 2 * RCH), TB, 0, stream>>>(
        pred, tgt, smask, part, bsum, cnts, out);
}

// Round 6
// 80.344 us; speedup vs baseline: 2.1475x; 2.1475x over previous
//
#include <hip/hip_runtime.h>
#include <math.h>

#define BB 32
#define NN 2048
#define TB 256            // k1 threads
#define QT 8              // queries per thread in k1 -> 2048 = NN per block
#define RCH 16            // ref chunks (split of the min over refs)
#define MCH (NN / RCH)    // 128 refs per chunk
#define TB2 512           // k2 threads

// ws layout: part[RCH][2*BB][NN] floats (8 MB, no init needed)

__device__ __forceinline__ float wred(float v) {
#pragma unroll
    for (int o = 32; o > 0; o >>= 1) v += __shfl_down(v, o, 64);
    return v;
}

// K1: grid (1, BB, 2*RCH); blockIdx.z = rc*2 + role. 1024 blocks = 4/CU.
// Partial min over one 128-ref chunk for all 2048 queries of (b, role).
// Block (y=0,z=0) also zeroes out[] — the k1->k2 dispatch boundary is the
// release fence (no device-scope __threadfence: R5 showed that costs ~100us).
__global__ __launch_bounds__(256) void k1_chamfer(
    const float* __restrict__ pred, const float* __restrict__ tgt,
    float* __restrict__ part, float* __restrict__ out)
{
    __shared__ float sa[MCH], sb[MCH], sc[MCH];

    const int tid  = threadIdx.x;
    const int b    = blockIdx.y;
    const int role = blockIdx.z & 1;
    const int rc   = blockIdx.z >> 1;

    if (b == 0 && blockIdx.z == 0 && tid < 4) out[tid] = 0.0f;

    const float* q = role ? tgt : pred;
    const float* r = role ? pred : tgt;
    const float* rb = r + ((size_t)b * NN + (size_t)rc * MCH) * 3;

    // Stage refs in norm form; invisible refs poisoned far (d2 ~ 2e18).
    if (tid < MCH) {
        float rx = rb[3 * tid + 0];
        float ry = rb[3 * tid + 1];
        float rv = rb[3 * tid + 2];
        if (rv != 1.0f) { rx = 1.0e9f; ry = 1.0e9f; }
        sa[tid] = -2.0f * rx;
        sb[tid] = -2.0f * ry;
        sc[tid] = fmaf(rx, rx, ry * ry);
    }
    __syncthreads();

    const float* qb_ = q + (size_t)b * NN * 3;
    float px[QT], py[QT], mn[QT];
#pragma unroll
    for (int j = 0; j < QT; j++) {
        int qi = tid + j * TB;
        px[j] = qb_[3 * qi + 0];
        py[j] = qb_[3 * qi + 1];
        mn[j] = 3.4e38f;
    }

    // 8 refs/iter: 6 uniform ds_read_b128 (broadcast, conflict-free),
    // per query 16 fma + 4 v_min3 -> 2.5 VALU/pair.
#pragma unroll 2
    for (int m = 0; m < MCH; m += 8) {
        float4 a0 = *(const float4*)&sa[m], a1 = *(const float4*)&sa[m + 4];
        float4 b0 = *(const float4*)&sb[m], b1 = *(const float4*)&sb[m + 4];
        float4 c0 = *(const float4*)&sc[m], c1 = *(const float4*)&sc[m + 4];
#pragma unroll
        for (int j = 0; j < QT; j++) {
            float s0 = fmaf(px[j], a0.x, fmaf(py[j], b0.x, c0.x));
            float s1 = fmaf(px[j], a0.y, fmaf(py[j], b0.y, c0.y));
            float s2 = fmaf(px[j], a0.z, fmaf(py[j], b0.z, c0.z));
            float s3 = fmaf(px[j], a0.w, fmaf(py[j], b0.w, c0.w));
            float s4 = fmaf(px[j], a1.x, fmaf(py[j], b1.x, c1.x));
            float s5 = fmaf(px[j], a1.y, fmaf(py[j], b1.y, c1.y));
            float s6 = fmaf(px[j], a1.z, fmaf(py[j], b1.z, c1.z));
            float s7 = fmaf(px[j], a1.w, fmaf(py[j], b1.w, c1.w));
            float u = fminf(fminf(s0, s1), s2);
            float v = fminf(fminf(s3, s4), s5);
            float w = fminf(fminf(s6, s7), mn[j]);
            mn[j] = fminf(fminf(u, v), w);
        }
    }

#pragma unroll
    for (int j = 0; j < QT; j++) {
        int qi = tid + j * TB;
        float qn = fmaf(px[j], px[j], py[j] * py[j]);
        part[((size_t)rc * (2 * BB) + role * BB + b) * NN + qi] = qn + mn[j];
    }
}

// K2: grid (BB) = 32 blocks, 512 threads. Block b owns batch b, BOTH roles:
// combine 16 planes per query, sqrt+mask epilogue, block-reduce 7 sums,
// compute chamfer_b locally, atomicAdd the (linear) output terms.
// The smk>0 gate is redundant: smk==0 => every st term is 0 => sum is 0.
__global__ __launch_bounds__(TB2) void k2_final(
    const float* __restrict__ pred, const float* __restrict__ tgt,
    const float* __restrict__ smask, const float* __restrict__ part,
    float* __restrict__ out)
{
    __shared__ float sred[7][8];
    const int tid = threadIdx.x;
    const int b   = blockIdx.x;

    float a0 = 0, a1 = 0, a2 = 0, a3 = 0, a4 = 0, a5 = 0, a6 = 0;

    // role 0 (queries = pred): contrib_p, cnt_p, point/struct/mask sums
#pragma unroll
    for (int j = 0; j < NN / TB2; j++) {
        int qi = tid + j * TB2;
        float m = 3.4e38f;
#pragma unroll
        for (int k = 0; k < RCH; k++)
            m = fminf(m, part[((size_t)k * (2 * BB) + b) * NN + qi]);

        const float* qp = pred + ((size_t)b * NN + qi) * 3;
        float qvf = (qp[2] == 1.0f) ? 1.0f : 0.0f;
        a0 += sqrtf(fmaxf(m, 1e-12f)) * qvf;
        a1 += qvf;

        const float* tp = tgt + ((size_t)b * NN + qi) * 3;
        float vm = (tp[2] == 1.0f) ? 1.0f : 0.0f;
        float dx = qp[0] - tp[0], dy = qp[1] - tp[1];
        float e2 = fmaf(dx, dx, dy * dy);
        float s0 = smask[((size_t)b * NN + qi) * 2 + 0];
        float s1 = smask[((size_t)b * NN + qi) * 2 + 1];
        float tm = fminf(fmaxf(s0 + s1, 0.0f), 1.0f) * vm;
        a2 += e2 * vm;
        a3 += e2 * tm;
        a4 += tm;
    }

    // role 1 (queries = tgt): contrib_t, cnt_t
#pragma unroll
    for (int j = 0; j < NN / TB2; j++) {
        int qi = tid + j * TB2;
        float m = 3.4e38f;
#pragma unroll
        for (int k = 0; k < RCH; k++)
            m = fminf(m, part[((size_t)k * (2 * BB) + BB + b) * NN + qi]);

        const float* qp = tgt + ((size_t)b * NN + qi) * 3;
        float qvf = (qp[2] == 1.0f) ? 1.0f : 0.0f;
        a5 += sqrtf(fmaxf(m, 1e-12f)) * qvf;
        a6 += qvf;
    }

    float v[7] = {a0, a1, a2, a3, a4, a5, a6};
    const int wave = tid >> 6, lane = tid & 63;
#pragma unroll
    for (int i = 0; i < 7; i++) {
        float rv = wred(v[i]);
        if (lane == 0) sred[i][wave] = rv;
    }
    __syncthreads();

    if (tid == 0) {
        float s[7];
#pragma unroll
        for (int i = 0; i < 7; i++) {
            float acc = 0.0f;
#pragma unroll
            for (int w = 0; w < TB2 / 64; w++) acc += sred[i][w];
            s[i] = acc;
        }
        float sp = s[0], cp = s[1], spt = s[2], sst = s[3];
        float st_ = s[5], ct = s[6];
        float mp = sp / fmaxf(cp, 1.0f);
        float mt = st_ / fmaxf(ct, 1.0f);
        float ch = (cp > 0.0f && ct > 0.0f) ? 0.5f * (mp + mt) : 0.0f;

        const float denom = (float)BB * (float)NN * 2.0f;
        float lp = spt / denom;          // loss_point contribution (batch b)
        float ls = sst / denom;          // loss_struct contribution
        float lc = ch / (float)BB;       // loss_chamfer contribution

        atomicAdd(&out[0], lp + 5.0f * lc + 2.0f * ls);
        atomicAdd(&out[1], lp);
        atomicAdd(&out[3], lc);
        // out[2] stays 0 (zeroed by k1)
    }
}

extern "C" void kernel_launch(void* const* d_in, const int* in_sizes, int n_in,
                              void* d_out, int out_size, void* d_ws, size_t ws_size,
                              hipStream_t stream)
{
    const float* pred  = (const float*)d_in[0];
    const float* tgt   = (const float*)d_in[1];
    const float* smask = (const float*)d_in[2];
    float* out = (float*)d_out;
    float* part = (float*)d_ws;   // 8 MB

    k1_chamfer<<<dim3(1, BB, 2 * RCH), TB, 0, stream>>>(pred, tgt, part, out);
    k2_final<<<dim3(BB), TB2, 0, stream>>>(pred, tgt, smask, part, out);
}